// Round 1
// baseline (244.279 us; speedup 1.0000x reference)
//
#include <hip/hip_runtime.h>
#include <math.h>

#define EPS 1e-4f
#define QAM_NORM 0.31622776601683794f  // 1/sqrt(10)

// One thread per site (B*T*S sites). M=16 antennas, K=4 streams, 16-QAM.
__global__ __launch_bounds__(256) void siso_pic_kernel(
    const float* __restrict__ y,     // (S,16,2)
    const float* __restrict__ h,     // (S,16,4,2)
    const float* __restrict__ llr_a, // (S,4,4)
    const float* __restrict__ no_p,  // (1,)
    float* __restrict__ out,         // (S,4,4)
    int nsites)
{
    int site = blockIdx.x * blockDim.x + threadIdx.x;
    if (site >= nsites) return;
    float no = no_p[0];

    // ---- accumulate G = H^H H (upper triangle) and y_mf = H^H y ----
    float Gre[4][4], Gim[4][4];
    float ymf_re[4], ymf_im[4];
    #pragma unroll
    for (int i = 0; i < 4; i++) {
        ymf_re[i] = 0.f; ymf_im[i] = 0.f;
        #pragma unroll
        for (int j = 0; j < 4; j++) { Gre[i][j] = 0.f; Gim[i][j] = 0.f; }
    }

    const float4* hp = reinterpret_cast<const float4*>(h + (size_t)site * 128);
    const float2* yp = reinterpret_cast<const float2*>(y + (size_t)site * 32);
    #pragma unroll
    for (int m = 0; m < 16; m++) {
        float4 hA = hp[2 * m];       // h[m][0].re, .im, h[m][1].re, .im
        float4 hB = hp[2 * m + 1];   // h[m][2].re, .im, h[m][3].re, .im
        float hre[4] = {hA.x, hA.z, hB.x, hB.z};
        float him[4] = {hA.y, hA.w, hB.y, hB.w};
        float2 yv = yp[m];
        #pragma unroll
        for (int i = 0; i < 4; i++) {
            // y_mf[i] += conj(h_i) * y
            ymf_re[i] += hre[i] * yv.x + him[i] * yv.y;
            ymf_im[i] += hre[i] * yv.y - him[i] * yv.x;
            #pragma unroll
            for (int j = i; j < 4; j++) {
                Gre[i][j] += hre[i] * hre[j] + him[i] * him[j];
                Gim[i][j] += hre[i] * him[j] - him[i] * hre[j];
            }
        }
    }
    // Hermitian mirror
    #pragma unroll
    for (int i = 0; i < 4; i++)
        #pragma unroll
        for (int j = 0; j < i; j++) { Gre[i][j] = Gre[j][i]; Gim[i][j] = -Gim[j][i]; }

    // ---- prior LLRs -> per-stream soft symbol, error variance, K_tilde ----
    float llr[4][4];
    const float4* lp = reinterpret_cast<const float4*>(llr_a + (size_t)site * 16);
    #pragma unroll
    for (int k = 0; k < 4; k++) {
        float4 v = lp[k];
        llr[k][0] = v.x; llr[k][1] = v.y; llr[k][2] = v.z; llr[k][3] = v.w;
    }

    float sh_re[4], sh_im[4], ev[4], Kt[4];
    #pragma unroll
    for (int k = 0; k < 4; k++) {
        float p0[4], p1[4];
        float kt = 0.f;
        #pragma unroll
        for (int j = 0; j < 4; j++) {
            float x = llr[k][j];
            float t = tanhf(0.5f * x);
            p0[j] = 0.5f * (1.f - t);
            p1[j] = 1.f - p0[j];
            float ax = fabsf(x);
            kt += 0.5f * ax + log1pf(expf(-ax));
        }
        Kt[k] = kt;
        float P[16];
        float sre = 0.f, sim = 0.f;
        #pragma unroll
        for (int i = 0; i < 16; i++) {
            int b0 = (i >> 3) & 1, b1 = (i >> 2) & 1, b2 = (i >> 1) & 1, b3 = i & 1;
            float Pv = (b0 ? p1[0] : p0[0]) * (b1 ? p1[1] : p0[1]) *
                       (b2 ? p1[2] : p0[2]) * (b3 ? p1[3] : p0[3]);
            P[i] = Pv;
            float pr = (float)((1 - 2 * b0) * (2 - (1 - 2 * b2))) * QAM_NORM;
            float pi = (float)((1 - 2 * b1) * (2 - (1 - 2 * b3))) * QAM_NORM;
            sre += pr * Pv; sim += pi * Pv;
        }
        sh_re[k] = sre; sh_im[k] = sim;
        float e = 0.f;
        #pragma unroll
        for (int i = 0; i < 16; i++) {
            int b0 = (i >> 3) & 1, b1 = (i >> 2) & 1, b2 = (i >> 1) & 1, b3 = i & 1;
            float pr = (float)((1 - 2 * b0) * (2 - (1 - 2 * b2))) * QAM_NORM;
            float pi = (float)((1 - 2 * b1) * (2 - (1 - 2 * b3))) * QAM_NORM;
            float dr = sre - pr, di = sim - pi;
            float d2 = fmaxf(dr * dr + di * di, EPS * EPS);
            e += d2 * P[i];
        }
        ev[k] = e;
    }

    // ---- A = G * diag(ev) + no*I ; in-place Gauss-Jordan inverse ----
    float Are[4][4], Aim[4][4];
    #pragma unroll
    for (int i = 0; i < 4; i++)
        #pragma unroll
        for (int j = 0; j < 4; j++) {
            Are[i][j] = Gre[i][j] * ev[j] + ((i == j) ? no : 0.f);
            Aim[i][j] = Gim[i][j] * ev[j];
        }
    #pragma unroll
    for (int p = 0; p < 4; p++) {
        float pr = Are[p][p], pi = Aim[p][p];
        float inv = 1.f / (pr * pr + pi * pi);
        float dre = pr * inv, dim = -pi * inv;   // 1/pivot
        Are[p][p] = 1.f; Aim[p][p] = 0.f;
        #pragma unroll
        for (int j = 0; j < 4; j++) {
            float ar = Are[p][j], ai = Aim[p][j];
            Are[p][j] = ar * dre - ai * dim;
            Aim[p][j] = ar * dim + ai * dre;
        }
        #pragma unroll
        for (int i = 0; i < 4; i++) {
            if (i == p) continue;
            float fr = Are[i][p], fi = Aim[i][p];
            Are[i][p] = 0.f; Aim[i][p] = 0.f;
            #pragma unroll
            for (int j = 0; j < 4; j++) {
                float br = Are[p][j], bi = Aim[p][j];
                Are[i][j] -= fr * br - fi * bi;
                Aim[i][j] -= fr * bi + fi * br;
            }
        }
    }

    // ---- resid = y_mf - G @ s_hat ; mu, z, rho ----
    float rr[4], ri[4];
    #pragma unroll
    for (int i = 0; i < 4; i++) {
        float ar = 0.f, ai = 0.f;
        #pragma unroll
        for (int j = 0; j < 4; j++) {
            ar += Gre[i][j] * sh_re[j] - Gim[i][j] * sh_im[j];
            ai += Gre[i][j] * sh_im[j] + Gim[i][j] * sh_re[j];
        }
        rr[i] = ymf_re[i] - ar; ri[i] = ymf_im[i] - ai;
    }
    float z_re[4], z_im[4], rho[4];
    #pragma unroll
    for (int k = 0; k < 4; k++) {
        float m_re = 0.f;
        #pragma unroll
        for (int j = 0; j < 4; j++)
            m_re += Are[k][j] * Gre[j][k] - Aim[k][j] * Gim[j][k];
        float m = fmaxf(m_re, EPS);
        float wr = 0.f, wi = 0.f;
        #pragma unroll
        for (int j = 0; j < 4; j++) {
            wr += Are[k][j] * rr[j] - Aim[k][j] * ri[j];
            wi += Are[k][j] * ri[j] + Aim[k][j] * rr[j];
        }
        z_re[k] = wr / m + sh_re[k];
        z_im[k] = wi / m + sh_im[k];
        rho[k] = m / fmaxf(1.f - ev[k] * m, EPS);
    }

    // ---- exponents and per-bit logsumexp LLRs ----
    float4* op = reinterpret_cast<float4*>(out + (size_t)site * 16);
    #pragma unroll
    for (int k = 0; k < 4; k++) {
        float ex[16];
        #pragma unroll
        for (int i = 0; i < 16; i++) {
            int b0 = (i >> 3) & 1, b1 = (i >> 2) & 1, b2 = (i >> 1) & 1, b3 = i & 1;
            float pr = (float)((1 - 2 * b0) * (2 - (1 - 2 * b2))) * QAM_NORM;
            float pi = (float)((1 - 2 * b1) * (2 - (1 - 2 * b3))) * QAM_NORM;
            float dr = z_re[k] - pr, di = z_im[k] - pi;
            float d2 = fmaxf(dr * dr + di * di, EPS * EPS);
            float dot = 0.5f * ((b0 ? llr[k][0] : -llr[k][0]) +
                                (b1 ? llr[k][1] : -llr[k][1]) +
                                (b2 ? llr[k][2] : -llr[k][2]) +
                                (b3 ? llr[k][3] : -llr[k][3]));
            ex[i] = -d2 * rho[k] + dot - Kt[k];
        }
        float res[4];
        #pragma unroll
        for (int j = 0; j < 4; j++) {
            float m1 = -1e30f, m0 = -1e30f;
            #pragma unroll
            for (int i = 0; i < 16; i++) {
                if ((i >> (3 - j)) & 1) m1 = fmaxf(m1, ex[i]);
                else                    m0 = fmaxf(m0, ex[i]);
            }
            float s1 = 0.f, s0 = 0.f;
            #pragma unroll
            for (int i = 0; i < 16; i++) {
                if ((i >> (3 - j)) & 1) s1 += expf(ex[i] - m1);
                else                    s0 += expf(ex[i] - m0);
            }
            res[j] = (m1 + logf(s1)) - (m0 + logf(s0));
        }
        op[k] = make_float4(res[0], res[1], res[2], res[3]);
    }
}

extern "C" void kernel_launch(void* const* d_in, const int* in_sizes, int n_in,
                              void* d_out, int out_size, void* d_ws, size_t ws_size,
                              hipStream_t stream) {
    const float* y    = (const float*)d_in[0];
    const float* h    = (const float*)d_in[1];
    const float* llr  = (const float*)d_in[2];
    const float* no   = (const float*)d_in[3];
    float* out = (float*)d_out;
    int nsites = in_sizes[2] / 16;   // B*T*S = 196608
    int threads = 256;
    int blocks = (nsites + threads - 1) / threads;
    siso_pic_kernel<<<blocks, threads, 0, stream>>>(y, h, llr, no, out, nsites);
}

// Round 2
// 210.339 us; speedup vs baseline: 1.1614x; 1.1614x over previous
//
#include <hip/hip_runtime.h>
#include <math.h>

#define EPS 1e-4f
#define QAM_NORM 0.31622776601683794f  // 1/sqrt(10)

// One thread per site (B*T*S sites). M=16 antennas, K=4 streams, 16-QAM.
// All transcendentals via native v_exp_f32 / v_log_f32 (__expf/__logf).
__global__ __launch_bounds__(256) void siso_pic_kernel(
    const float* __restrict__ y,     // (S,16,2)
    const float* __restrict__ h,     // (S,16,4,2)
    const float* __restrict__ llr_a, // (S,4,4)
    const float* __restrict__ no_p,  // (1,)
    float* __restrict__ out,         // (S,4,4)
    int nsites)
{
    int site = blockIdx.x * blockDim.x + threadIdx.x;
    if (site >= nsites) return;
    const float no = no_p[0];

    // ---------------- priors: p0 via sigmoid (shares exp with K_tilde) ----
    const float4* lp = reinterpret_cast<const float4*>(llr_a + (size_t)site * 16);
    float llr[4][4];
    #pragma unroll
    for (int k = 0; k < 4; k++) {
        float4 v = lp[k];
        llr[k][0] = v.x; llr[k][1] = v.y; llr[k][2] = v.z; llr[k][3] = v.w;
    }

    float sh_re[4], sh_im[4], ev[4], Kt[4];
    #pragma unroll
    for (int k = 0; k < 4; k++) {
        float p0[4];
        float kt = 0.f;
        #pragma unroll
        for (int j = 0; j < 4; j++) {
            float x = llr[k][j];
            float ax = fabsf(x);
            float e = __expf(-ax);           // e^{-|x|} in (0,1]
            float r = 1.f / (1.f + e);
            p0[j] = (x >= 0.f) ? e * r : r;  // sigmoid(-x) == 0.5*(1-tanh(x/2))
            kt += 0.5f * ax + __logf(1.f + e);
        }
        Kt[k] = kt;
        // soft symbol, closed form: t = 2*p0-1 = -tanh(x/2)
        float t0 = 2.f * p0[0] - 1.f, t1 = 2.f * p0[1] - 1.f;
        float t2 = 2.f * p0[2] - 1.f, t3 = 2.f * p0[3] - 1.f;
        float sre = QAM_NORM * t0 * (2.f - t2);
        float sim = QAM_NORM * t1 * (2.f - t3);
        sh_re[k] = sre; sh_im[k] = sim;
        // pair probability tables (temporaries, die after err_var)
        float p1_0 = 1.f - p0[0], p1_1 = 1.f - p0[1];
        float p1_2 = 1.f - p0[2], p1_3 = 1.f - p0[3];
        float pA[4] = { p0[0]*p0[1], p0[0]*p1_1, p1_0*p0[1], p1_0*p1_1 };
        float pB[4] = { p0[2]*p0[3], p0[2]*p1_3, p1_2*p0[3], p1_2*p1_3 };
        // err_var with the reference's exact per-point clamp
        float e2 = 0.f;
        #pragma unroll
        for (int i = 0; i < 16; i++) {
            int b0 = (i >> 3) & 1, b1 = (i >> 2) & 1, b2 = (i >> 1) & 1, b3 = i & 1;
            float pr = (float)((1 - 2*b0) * (1 + 2*b2)) * QAM_NORM;
            float pi = (float)((1 - 2*b1) * (1 + 2*b3)) * QAM_NORM;
            float P = pA[(b0<<1)|b1] * pB[(b2<<1)|b3];
            float dr = sre - pr, di = sim - pi;
            float d2 = fmaxf(dr*dr + di*di, EPS*EPS);
            e2 += d2 * P;
        }
        ev[k] = e2;
    }

    // ---------------- G = H^H H (upper) and y_mf = H^H y ------------------
    float Gre[4][4], Gim[4][4];
    float ymf_re[4], ymf_im[4];
    #pragma unroll
    for (int i = 0; i < 4; i++) {
        ymf_re[i] = 0.f; ymf_im[i] = 0.f;
        #pragma unroll
        for (int j = 0; j < 4; j++) { Gre[i][j] = 0.f; Gim[i][j] = 0.f; }
    }
    const float4* hp = reinterpret_cast<const float4*>(h + (size_t)site * 128);
    const float2* yp = reinterpret_cast<const float2*>(y + (size_t)site * 32);
    #pragma unroll
    for (int m = 0; m < 16; m++) {
        float4 hA = hp[2 * m];
        float4 hB = hp[2 * m + 1];
        float hre[4] = {hA.x, hA.z, hB.x, hB.z};
        float him[4] = {hA.y, hA.w, hB.y, hB.w};
        float2 yv = yp[m];
        #pragma unroll
        for (int i = 0; i < 4; i++) {
            ymf_re[i] += hre[i] * yv.x + him[i] * yv.y;
            ymf_im[i] += hre[i] * yv.y - him[i] * yv.x;
            #pragma unroll
            for (int j = i; j < 4; j++) {
                Gre[i][j] += hre[i] * hre[j] + him[i] * him[j];
                Gim[i][j] += hre[i] * him[j] - him[i] * hre[j];
            }
        }
    }
    #pragma unroll
    for (int i = 0; i < 4; i++)
        #pragma unroll
        for (int j = 0; j < i; j++) { Gre[i][j] = Gre[j][i]; Gim[i][j] = -Gim[j][i]; }

    // ---------------- A = G*diag(ev) + no*I ; Gauss-Jordan inverse --------
    float Are[4][4], Aim[4][4];
    #pragma unroll
    for (int i = 0; i < 4; i++)
        #pragma unroll
        for (int j = 0; j < 4; j++) {
            Are[i][j] = Gre[i][j] * ev[j] + ((i == j) ? no : 0.f);
            Aim[i][j] = Gim[i][j] * ev[j];
        }
    #pragma unroll
    for (int p = 0; p < 4; p++) {
        float pr = Are[p][p], pi = Aim[p][p];
        float inv = 1.f / (pr * pr + pi * pi);
        float dre = pr * inv, dim = -pi * inv;
        Are[p][p] = 1.f; Aim[p][p] = 0.f;
        #pragma unroll
        for (int j = 0; j < 4; j++) {
            float ar = Are[p][j], ai = Aim[p][j];
            Are[p][j] = ar * dre - ai * dim;
            Aim[p][j] = ar * dim + ai * dre;
        }
        #pragma unroll
        for (int i = 0; i < 4; i++) {
            if (i == p) continue;
            float fr = Are[i][p], fi = Aim[i][p];
            Are[i][p] = 0.f; Aim[i][p] = 0.f;
            #pragma unroll
            for (int j = 0; j < 4; j++) {
                float br = Are[p][j], bi = Aim[p][j];
                Are[i][j] -= fr * br - fi * bi;
                Aim[i][j] -= fr * bi + fi * br;
            }
        }
    }

    // ---------------- resid, mu, z, rho -----------------------------------
    float rr[4], ri[4];
    #pragma unroll
    for (int i = 0; i < 4; i++) {
        float ar = 0.f, ai = 0.f;
        #pragma unroll
        for (int j = 0; j < 4; j++) {
            ar += Gre[i][j] * sh_re[j] - Gim[i][j] * sh_im[j];
            ai += Gre[i][j] * sh_im[j] + Gim[i][j] * sh_re[j];
        }
        rr[i] = ymf_re[i] - ar; ri[i] = ymf_im[i] - ai;
    }
    float z_re[4], z_im[4], rho[4];
    #pragma unroll
    for (int k = 0; k < 4; k++) {
        float m_re = 0.f;
        #pragma unroll
        for (int j = 0; j < 4; j++)
            m_re += Are[k][j] * Gre[j][k] - Aim[k][j] * Gim[j][k];
        float m = fmaxf(m_re, EPS);
        float wr = 0.f, wi = 0.f;
        #pragma unroll
        for (int j = 0; j < 4; j++) {
            wr += Are[k][j] * rr[j] - Aim[k][j] * ri[j];
            wi += Are[k][j] * ri[j] + Aim[k][j] * rr[j];
        }
        float minv = 1.f / m;
        z_re[k] = wr * minv + sh_re[k];
        z_im[k] = wi * minv + sh_im[k];
        rho[k] = m / fmaxf(1.f - ev[k] * m, EPS);
    }

    // ---------------- exponents + per-bit logsumexp LLRs ------------------
    float4* op = reinterpret_cast<float4*>(out + (size_t)site * 16);
    #pragma unroll
    for (int k = 0; k < 4; k++) {
        float l0 = llr[k][0], l1 = llr[k][1], l2 = llr[k][2], l3 = llr[k][3];
        float kt = Kt[k];
        // dot tables with -Kt folded into dA; index (b_hi<<1)|b_lo
        float dA[4] = { -0.5f*(l0+l1) - kt, -0.5f*(l0-l1) - kt,
                         0.5f*(l0-l1) - kt,  0.5f*(l0+l1) - kt };
        float dB[4] = { -0.5f*(l2+l3), -0.5f*(l2-l3),
                         0.5f*(l2-l3),  0.5f*(l2+l3) };
        float zr = z_re[k], zi = z_im[k], rh = rho[k];
        float ex[16];
        #pragma unroll
        for (int i = 0; i < 16; i++) {
            int b0 = (i >> 3) & 1, b1 = (i >> 2) & 1, b2 = (i >> 1) & 1, b3 = i & 1;
            float pr = (float)((1 - 2*b0) * (1 + 2*b2)) * QAM_NORM;
            float pi = (float)((1 - 2*b1) * (1 + 2*b3)) * QAM_NORM;
            float dr = zr - pr, di = zi - pi;
            float d2 = fmaxf(dr*dr + di*di, EPS*EPS);
            ex[i] = -d2 * rh + dA[(b0<<1)|b1] + dB[(b2<<1)|b3];
        }
        float res[4];
        #pragma unroll
        for (int j = 0; j < 4; j++) {
            float m1 = -1e30f, m0 = -1e30f;
            #pragma unroll
            for (int i = 0; i < 16; i++) {
                if ((i >> (3 - j)) & 1) m1 = fmaxf(m1, ex[i]);
                else                    m0 = fmaxf(m0, ex[i]);
            }
            float s1 = 0.f, s0 = 0.f;
            #pragma unroll
            for (int i = 0; i < 16; i++) {
                if ((i >> (3 - j)) & 1) s1 += __expf(ex[i] - m1);
                else                    s0 += __expf(ex[i] - m0);
            }
            res[j] = (m1 - m0) + (__logf(s1) - __logf(s0));
        }
        op[k] = make_float4(res[0], res[1], res[2], res[3]);
    }
}

extern "C" void kernel_launch(void* const* d_in, const int* in_sizes, int n_in,
                              void* d_out, int out_size, void* d_ws, size_t ws_size,
                              hipStream_t stream) {
    const float* y    = (const float*)d_in[0];
    const float* h    = (const float*)d_in[1];
    const float* llr  = (const float*)d_in[2];
    const float* no   = (const float*)d_in[3];
    float* out = (float*)d_out;
    int nsites = in_sizes[2] / 16;   // B*T*S = 196608
    int threads = 256;
    int blocks = (nsites + threads - 1) / threads;
    siso_pic_kernel<<<blocks, threads, 0, stream>>>(y, h, llr, no, out, nsites);
}